// Round 9
// baseline (664.447 us; speedup 1.0000x reference)
//
#include <hip/hip_runtime.h>

#define IN_F 256
#define HID  128
#define NCLS 40
#define NBKT 256        // coarse buckets of 512 nodes: supports N <= 131072
#define BKTSH 9         // 512 nodes per bucket
#define CH 16384        // edges per binning chunk
#define NSL 8           // feature slices for agg1 (16 cols each)

typedef __attribute__((ext_vector_type(8))) short bf16x8;
typedef __attribute__((ext_vector_type(4))) float f32x4;

static __device__ __forceinline__ unsigned short f2bf(float f) {
    unsigned u = __builtin_bit_cast(unsigned, f);
    u += 0x7fffu + ((u >> 16) & 1u);   // round-to-nearest-even
    return (unsigned short)(u >> 16);
}

// ---------------- zero ----------------
__global__ void zero4_kernel(float4* __restrict__ p, int n4) {
    int i = blockIdx.x * blockDim.x + threadIdx.x;
    if (i < n4) p[i] = make_float4(0.f, 0.f, 0.f, 0.f);
}

// ---------------- count: LDS coarse-bucket histogram + global out-degree ----------------
__global__ __launch_bounds__(256) void count_kernel(
    const int* __restrict__ src, const int* __restrict__ dst,
    int* __restrict__ cnt_out, int* __restrict__ bktCnt, int E) {
    __shared__ int hist[NBKT];
    hist[threadIdx.x] = 0;
    __syncthreads();
    int stride = gridDim.x * 256;
    for (int i = blockIdx.x * 256 + threadIdx.x; i < E; i += stride) {
        atomicAdd(&cnt_out[src[i]], 1);
        atomicAdd(&hist[dst[i] >> BKTSH], 1);
    }
    __syncthreads();
    int c = hist[threadIdx.x];
    if (c) atomicAdd(&bktCnt[threadIdx.x], c);
}

// ---------------- bucket exclusive scan (one block, 256 entries) ----------------
__global__ __launch_bounds__(256) void bscan_kernel(const int* __restrict__ bktCnt,
                                                    int* __restrict__ bktBase,
                                                    int* __restrict__ bktCursor) {
    __shared__ int s[256];
    int t = threadIdx.x;
    int v = bktCnt[t];
    s[t] = v;
    __syncthreads();
    for (int off = 1; off < 256; off <<= 1) {
        int u = (t >= off) ? s[t - off] : 0;
        __syncthreads();
        s[t] += u;
        __syncthreads();
    }
    int excl = s[t] - v;
    bktBase[t] = excl;
    bktCursor[t] = excl;
    if (t == 255) bktBase[256] = s[t];   // total = E
}

__global__ void rsout_kernel(const int* __restrict__ cnt_out, float* __restrict__ rs_out, int N) {
    int i = blockIdx.x * blockDim.x + threadIdx.x;
    if (i < N) rs_out[i] = rsqrtf((float)max(cnt_out[i], 1));
}

// ---------------- binA: two-pass chunk -> dense per-bucket appends ----------------
__global__ __launch_bounds__(256) void binA_kernel(
    const int* __restrict__ src, const int* __restrict__ dst,
    int* __restrict__ bktCursor, int* __restrict__ bin, int E) {
    __shared__ int cnt[NBKT];
    __shared__ int ofs[NBKT];
    const int tx = threadIdx.x;
    const int be = blockIdx.x * CH;
    const int ee = min(be + CH, E);
    cnt[tx] = 0;
    __syncthreads();
    for (int i = be + tx; i < ee; i += 256)
        atomicAdd(&cnt[dst[i] >> BKTSH], 1);
    __syncthreads();
    int c = cnt[tx];
    ofs[tx] = c ? atomicAdd(&bktCursor[tx], c) : 0;   // bulk reservation
    cnt[tx] = 0;                                       // reuse as local cursor
    __syncthreads();
    for (int i = be + tx; i < ee; i += 256) {
        int d = dst[i];
        int b = d >> BKTSH;
        int l = atomicAdd(&cnt[b], 1);
        bin[ofs[b] + l] = ((d & 511) << 17) | src[i];  // src < 2^17
    }
}

// ---------------- passB: per-bucket (512 nodes) LDS counting sort ----------------
__global__ __launch_bounds__(256) void passB_kernel(
    const int* __restrict__ bktBase, const int* __restrict__ bin,
    int* __restrict__ csr_src, int* __restrict__ row_ptr, float* __restrict__ rs_in, int N) {
    __shared__ int cnt[512];
    __shared__ int cur[512];
    __shared__ int part[256];
    const int b = blockIdx.x;
    const int base = bktBase[b], end = bktBase[b + 1];
    const int tx = threadIdx.x;
    cnt[tx] = 0; cnt[tx + 256] = 0;
    __syncthreads();
    for (int i = base + tx; i < end; i += 256)
        atomicAdd(&cnt[bin[i] >> 17], 1);
    __syncthreads();
    // exclusive scan over 512 (2 entries/thread)
    int a0 = cnt[2 * tx], a1 = cnt[2 * tx + 1];
    part[tx] = a0 + a1;
    __syncthreads();
    for (int off = 1; off < 256; off <<= 1) {
        int v = (tx >= off) ? part[tx - off] : 0;
        __syncthreads();
        part[tx] += v;
        __syncthreads();
    }
    int excl = part[tx] - (a0 + a1);
    cur[2 * tx] = excl;
    cur[2 * tx + 1] = excl + a0;
    int idx = (b << BKTSH) + 2 * tx;
    row_ptr[idx]     = base + excl;
    row_ptr[idx + 1] = base + excl + a0;
    if (idx < N)     rs_in[idx]     = rsqrtf((float)max(a0, 1));
    if (idx + 1 < N) rs_in[idx + 1] = rsqrtf((float)max(a1, 1));
    __syncthreads();
    for (int i = base + tx; i < end; i += 256) {
        int v = bin[i];
        int nl = v >> 17;
        int p = atomicAdd(&cur[nl], 1);
        csr_src[base + p] = v & 0x1FFFF;
    }
}

// ---------------- GEMM1 (MFMA bf16): h1s = bf16((x*rs_out) @ W1), SLICE-MAJOR ------------
// h1s layout: [slice=col/16][node][col%16]  (8 slices x N x 16 bf16, 32 B per node-slice)
__global__ __launch_bounds__(256) void gemm1_kernel(
    const float* __restrict__ x, const float* __restrict__ W1,
    const float* __restrict__ rs_out, unsigned short* __restrict__ h1s, int N) {
    __shared__ unsigned short Wl[32768];  // 64 KB

    const int tx = threadIdx.x;
#pragma unroll
    for (int e = 0; e < 32; ++e) {
        int base = (tx + 256 * e) * 4;
        float4 w = *(const float4*)&W1[base];
        int k = base >> 7;
        int c0 = base & 127;
        float wv[4] = {w.x, w.y, w.z, w.w};
#pragma unroll
        for (int q = 0; q < 4; ++q) {
            int col = c0 + q;
            int byte = col * 512 + k * 2;
            byte ^= (col & 7) << 4;
            Wl[byte >> 1] = f2bf(wv[q]);
        }
    }
    __syncthreads();

    const int wv_ = tx >> 6, lane = tx & 63;
    const int r0 = blockIdx.x * 64 + wv_ * 16;
    const int arow = r0 + (lane & 15);
    const int arow_c = min(arow, N - 1);
    const float rs = rs_out[arow_c];
    const long xbase = (long)arow_c * IN_F + (lane >> 4) * 8;

    bf16x8 a8[8];
#pragma unroll
    for (int ks = 0; ks < 8; ++ks) {
        float4 p0 = *(const float4*)&x[xbase + ks * 32];
        float4 p1 = *(const float4*)&x[xbase + ks * 32 + 4];
        bf16x8 a;
        a[0] = (short)f2bf(p0.x * rs); a[1] = (short)f2bf(p0.y * rs);
        a[2] = (short)f2bf(p0.z * rs); a[3] = (short)f2bf(p0.w * rs);
        a[4] = (short)f2bf(p1.x * rs); a[5] = (short)f2bf(p1.y * rs);
        a[6] = (short)f2bf(p1.z * rs); a[7] = (short)f2bf(p1.w * rs);
        a8[ks] = a;
    }

    f32x4 acc[8];
#pragma unroll
    for (int nf = 0; nf < 8; ++nf) acc[nf] = (f32x4){0.f, 0.f, 0.f, 0.f};

#pragma unroll
    for (int ks = 0; ks < 8; ++ks) {
#pragma unroll
        for (int nf = 0; nf < 8; ++nf) {
            int col = nf * 16 + (lane & 15);
            int kb  = ks * 32 + (lane >> 4) * 8;
            int byte = col * 512 + kb * 2;
            byte ^= (col & 7) << 4;
            bf16x8 b = *(const bf16x8*)((const char*)Wl + byte);
            acc[nf] = __builtin_amdgcn_mfma_f32_16x16x32_bf16(a8[ks], b, acc[nf], 0, 0, 0);
        }
    }

    // store slice-major: slice nf, node row, col lane&15
#pragma unroll
    for (int nf = 0; nf < 8; ++nf) {
#pragma unroll
        for (int j = 0; j < 4; ++j) {
            int row = r0 + (lane >> 4) * 4 + j;
            if (row < N)
                h1s[(long)nf * N * 16 + (long)row * 16 + (lane & 15)] = f2bf(acc[nf][j]);
        }
    }
}

// ---------------- agg1 (pull, XCD-affine slices): agg[n][s*16..] = sum h1s[s][src] ------
// grid: blocks with slice = blockIdx%8 -> round-robin XCD mapping keeps each 3.2 MB slice
// resident in one XCD's L2. Wave = 8 edges x 8 lanes (32 B per edge-slice).
__global__ __launch_bounds__(256) void agg1_kernel(
    const int* __restrict__ row_ptr, const int* __restrict__ csr_src,
    const unsigned* __restrict__ h1su,  // uint view of h1s: [8][N][8] uint
    float* __restrict__ agg, int N) {
    const int s    = blockIdx.x & 7;
    const int cb   = blockIdx.x >> 3;
    const int wv   = threadIdx.x >> 6;
    const int lane = threadIdx.x & 63;
    const int grp  = lane >> 3;          // edge group 0..7
    const int l8   = lane & 7;           // uint within 32B slice row
    const unsigned* hs = h1su + (long)s * N * 8;
    const int nstride = (gridDim.x >> 3) * 4;

    for (int node = cb * 4 + wv; node < N; node += nstride) {
        int e0 = row_ptr[node], e1 = row_ptr[node + 1];
        float a0 = 0.f, a1 = 0.f;
        for (int e = e0 + grp; e < e1; e += 8) {
            unsigned u = hs[(long)csr_src[e] * 8 + l8];
            a0 += __builtin_bit_cast(float, u << 16);
            a1 += __builtin_bit_cast(float, u & 0xffff0000u);
        }
        // reduce across the 8 edge groups
#pragma unroll
        for (int m = 8; m < 64; m <<= 1) {
            a0 += __shfl_xor(a0, m);
            a1 += __shfl_xor(a1, m);
        }
        if (grp == 0) {
            float2 o; o.x = a0; o.y = a1;
            *(float2*)&agg[(long)node * HID + s * 16 + 2 * l8] = o;
        }
    }
}

// -------- GEMM2 (MFMA bf16): h2b = bf16((relu(agg*rs_in+b1)*rs_out) @ W2) [N,128]@[128,40]
// W2 staged in LDS col-major [48 cols][128 k] bf16, swizzled; cols 40..47 zero.
__global__ __launch_bounds__(256) void gemm2_kernel(
    const float* __restrict__ agg1, const float* __restrict__ W2,
    const float* __restrict__ b1, const float* __restrict__ rs_in,
    const float* __restrict__ rs_out, unsigned short* __restrict__ h2b, int N) {
    __shared__ unsigned short Wl[48 * 128];  // 12 KB

    const int tx = threadIdx.x;
    for (int idx = tx; idx < 48 * 128; idx += 256) Wl[idx] = 0;
    __syncthreads();
    for (int idx = tx; idx < 128 * NCLS; idx += 256) {
        int k = idx / NCLS, c = idx - k * NCLS;
        int byte = c * 256 + k * 2;
        byte ^= (c & 7) << 4;
        Wl[byte >> 1] = f2bf(W2[idx]);
    }
    __syncthreads();

    const int wv_ = tx >> 6, lane = tx & 63;
    const int r0 = blockIdx.x * 64 + wv_ * 16;
    const int arow = r0 + (lane & 15);
    const int arow_c = min(arow, N - 1);
    const float ri = rs_in[arow_c];
    const float ro = rs_out[arow_c];
    const int k0 = (lane >> 4) * 8;
    const long abase = (long)arow_c * HID + k0;

    bf16x8 a8[4];
#pragma unroll
    for (int ks = 0; ks < 4; ++ks) {
        float4 p0 = *(const float4*)&agg1[abase + ks * 32];
        float4 p1 = *(const float4*)&agg1[abase + ks * 32 + 4];
        float4 c0 = *(const float4*)&b1[k0 + ks * 32];
        float4 c1 = *(const float4*)&b1[k0 + ks * 32 + 4];
        bf16x8 a;
        a[0] = (short)f2bf(fmaxf(fmaf(p0.x, ri, c0.x), 0.f) * ro);
        a[1] = (short)f2bf(fmaxf(fmaf(p0.y, ri, c0.y), 0.f) * ro);
        a[2] = (short)f2bf(fmaxf(fmaf(p0.z, ri, c0.z), 0.f) * ro);
        a[3] = (short)f2bf(fmaxf(fmaf(p0.w, ri, c0.w), 0.f) * ro);
        a[4] = (short)f2bf(fmaxf(fmaf(p1.x, ri, c1.x), 0.f) * ro);
        a[5] = (short)f2bf(fmaxf(fmaf(p1.y, ri, c1.y), 0.f) * ro);
        a[6] = (short)f2bf(fmaxf(fmaf(p1.z, ri, c1.z), 0.f) * ro);
        a[7] = (short)f2bf(fmaxf(fmaf(p1.w, ri, c1.w), 0.f) * ro);
        a8[ks] = a;
    }

    f32x4 acc[3];
#pragma unroll
    for (int nf = 0; nf < 3; ++nf) acc[nf] = (f32x4){0.f, 0.f, 0.f, 0.f};

#pragma unroll
    for (int ks = 0; ks < 4; ++ks) {
#pragma unroll
        for (int nf = 0; nf < 3; ++nf) {
            int col = nf * 16 + (lane & 15);
            int kb  = ks * 32 + k0;
            int byte = col * 256 + kb * 2;
            byte ^= (col & 7) << 4;
            bf16x8 b = *(const bf16x8*)((const char*)Wl + byte);
            acc[nf] = __builtin_amdgcn_mfma_f32_16x16x32_bf16(a8[ks], b, acc[nf], 0, 0, 0);
        }
    }

#pragma unroll
    for (int nf = 0; nf < 3; ++nf) {
        int col = nf * 16 + (lane & 15);
        if (col < NCLS) {
#pragma unroll
            for (int j = 0; j < 4; ++j) {
                int row = r0 + (lane >> 4) * 4 + j;
                if (row < N)
                    h2b[(long)row * NCLS + col] = f2bf(acc[nf][j]);
            }
        }
    }
}

// ---------------- agg2 (pull) + epilogue: thread per (node, col-pair) -------------------
__global__ __launch_bounds__(256) void agg2_kernel(
    const int* __restrict__ row_ptr, const int* __restrict__ row_end,
    const int* __restrict__ csr_src, const unsigned* __restrict__ h2b2,  // [N][20] uint
    const float* __restrict__ rs_in, const float* __restrict__ b2,
    float* __restrict__ out, int N) {
    int i = blockIdx.x * 256 + threadIdx.x;
    if (i >= N * 20) return;
    int node = i / 20;
    int cp   = i - node * 20;
    int e = row_ptr[node], end = row_end[node];
    float ax = 0.f, ay = 0.f;
    for (; e + 4 <= end; e += 4) {
        int s0 = csr_src[e], s1 = csr_src[e + 1], s2 = csr_src[e + 2], s3 = csr_src[e + 3];
        unsigned u0 = h2b2[(long)s0 * 20 + cp];
        unsigned u1 = h2b2[(long)s1 * 20 + cp];
        unsigned u2 = h2b2[(long)s2 * 20 + cp];
        unsigned u3 = h2b2[(long)s3 * 20 + cp];
        ax += __builtin_bit_cast(float, u0 << 16) + __builtin_bit_cast(float, u1 << 16)
            + __builtin_bit_cast(float, u2 << 16) + __builtin_bit_cast(float, u3 << 16);
        ay += __builtin_bit_cast(float, u0 & 0xffff0000u) + __builtin_bit_cast(float, u1 & 0xffff0000u)
            + __builtin_bit_cast(float, u2 & 0xffff0000u) + __builtin_bit_cast(float, u3 & 0xffff0000u);
    }
    for (; e < end; ++e) {
        unsigned u = h2b2[(long)csr_src[e] * 20 + cp];
        ax += __builtin_bit_cast(float, u << 16);
        ay += __builtin_bit_cast(float, u & 0xffff0000u);
    }
    float r = rs_in[node];
    float2 o;
    o.x = fmaf(ax, r, b2[2 * cp]);
    o.y = fmaf(ay, r, b2[2 * cp + 1]);
    *(float2*)&out[(long)node * NCLS + 2 * cp] = o;
}

extern "C" void kernel_launch(void* const* d_in, const int* in_sizes, int n_in,
                              void* d_out, int out_size, void* d_ws, size_t ws_size,
                              hipStream_t stream) {
    const float* x  = (const float*)d_in[0];
    const float* W1 = (const float*)d_in[1];
    const float* b1 = (const float*)d_in[2];
    const float* W2 = (const float*)d_in[3];
    const float* b2 = (const float*)d_in[4];
    const int*  src = (const int*)d_in[5];
    const int*  dst = (const int*)d_in[6];
    const int N = in_sizes[0] / IN_F;
    const int E = in_sizes[5];

    float* wsf      = (float*)d_ws;
    float* rs_out   = wsf;                         // N f
    float* rs_in    = wsf + N;                     // N f
    int*   cnt_out  = (int*)(wsf + 2 * (long)N);   // N i   (zeroed, contiguous w/ bktCnt)
    int*   bktCnt   = cnt_out + N;                 // NBKT i (zeroed)
    int*   bktBase  = bktCnt + NBKT;               // NBKT+4 i
    int*   bktCursor= bktBase + NBKT + 4;          // NBKT i
    int*   row_ptr  = bktCursor + NBKT;            // N+1024 i
    int*   bin      = row_ptr + N + 1024;          // E i
    int*   csr_src  = bin + E;                     // E i
    unsigned short* h1s = (unsigned short*)(csr_src + E);          // 8*N*16 bf16 slice-major
    float* agg1     = (float*)(h1s + (long)NSL * N * 16);          // N*128 f
    unsigned short* h2b = (unsigned short*)(agg1 + (long)N * HID); // N*40 bf16

    // zero cnt_out + bktCnt (contiguous)
    {
        int n4 = (N + NBKT) / 4;
        zero4_kernel<<<(n4 + 255) / 256, 256, 0, stream>>>((float4*)cnt_out, n4);
    }

    count_kernel<<<256, 256, 0, stream>>>(src, dst, cnt_out, bktCnt, E);
    bscan_kernel<<<1, 256, 0, stream>>>(bktCnt, bktBase, bktCursor);
    rsout_kernel<<<(N + 255) / 256, 256, 0, stream>>>(cnt_out, rs_out, N);
    binA_kernel<<<(E + CH - 1) / CH, 256, 0, stream>>>(src, dst, bktCursor, bin, E);
    passB_kernel<<<(N + 511) / 512, 256, 0, stream>>>(bktBase, bin, csr_src, row_ptr, rs_in, N);

    gemm1_kernel<<<(N + 63) / 64, 256, 0, stream>>>(x, W1, rs_out, h1s, N);
    agg1_kernel<<<2048, 256, 0, stream>>>(row_ptr, csr_src, (const unsigned*)h1s, agg1, N);
    gemm2_kernel<<<(N + 63) / 64, 256, 0, stream>>>(agg1, W2, b1, rs_in, rs_out, h2b, N);
    agg2_kernel<<<(N * 20 + 255) / 256, 256, 0, stream>>>(row_ptr, row_ptr + 1, csr_src,
                                                          (const unsigned*)h2b, rs_in, b2,
                                                          (float*)d_out, N);
}

// Round 10
// 493.888 us; speedup vs baseline: 1.3453x; 1.3453x over previous
//
#include <hip/hip_runtime.h>

#define IN_F 256
#define HID  128
#define NCLS 40
#define NBKT 256        // coarse buckets of 512 nodes: supports N <= 131072
#define BKTSH 9         // 512 nodes per bucket
#define CH 16384        // edges per binning chunk

typedef __attribute__((ext_vector_type(8))) short bf16x8;
typedef __attribute__((ext_vector_type(4))) float f32x4;

static __device__ __forceinline__ unsigned short f2bf(float f) {
    unsigned u = __builtin_bit_cast(unsigned, f);
    u += 0x7fffu + ((u >> 16) & 1u);   // round-to-nearest-even
    return (unsigned short)(u >> 16);
}

// ---------------- zero (tiny: bucket counters only) ----------------
__global__ void zero_kernel(int* __restrict__ p, int n) {
    int i = blockIdx.x * blockDim.x + threadIdx.x;
    if (i < n) p[i] = 0;
}

// ---------------- count: LDS bucket histograms for BOTH src and dst ----------------
__global__ __launch_bounds__(256) void count_kernel(
    const int* __restrict__ src, const int* __restrict__ dst,
    int* __restrict__ bktCntD, int* __restrict__ bktCntS, int E) {
    __shared__ int histD[NBKT];
    __shared__ int histS[NBKT];
    histD[threadIdx.x] = 0;
    histS[threadIdx.x] = 0;
    __syncthreads();
    int stride = gridDim.x * 256;
    for (int i = blockIdx.x * 256 + threadIdx.x; i < E; i += stride) {
        atomicAdd(&histD[dst[i] >> BKTSH], 1);
        atomicAdd(&histS[src[i] >> BKTSH], 1);
    }
    __syncthreads();
    int c = histD[threadIdx.x];
    if (c) atomicAdd(&bktCntD[threadIdx.x], c);
    c = histS[threadIdx.x];
    if (c) atomicAdd(&bktCntS[threadIdx.x], c);
}

// ---------------- bucket exclusive scan (one block, 256 entries) ----------------
__global__ __launch_bounds__(256) void bscan_kernel(const int* __restrict__ bktCnt,
                                                    int* __restrict__ bktBase,
                                                    int* __restrict__ bktCursor) {
    __shared__ int s[256];
    int t = threadIdx.x;
    int v = bktCnt[t];
    s[t] = v;
    __syncthreads();
    for (int off = 1; off < 256; off <<= 1) {
        int u = (t >= off) ? s[t - off] : 0;
        __syncthreads();
        s[t] += u;
        __syncthreads();
    }
    int excl = s[t] - v;
    bktBase[t] = excl;
    bktCursor[t] = excl;
    if (t == 255) bktBase[256] = s[t];   // total = E
}

// ---------------- binA_dst: two-pass chunk -> dense per-bucket appends (int payload) ----
__global__ __launch_bounds__(256) void binA_kernel(
    const int* __restrict__ src, const int* __restrict__ dst,
    int* __restrict__ bktCursor, int* __restrict__ bin, int E) {
    __shared__ int cnt[NBKT];
    __shared__ int ofs[NBKT];
    const int tx = threadIdx.x;
    const int be = blockIdx.x * CH;
    const int ee = min(be + CH, E);
    cnt[tx] = 0;
    __syncthreads();
    for (int i = be + tx; i < ee; i += 256)
        atomicAdd(&cnt[dst[i] >> BKTSH], 1);
    __syncthreads();
    int c = cnt[tx];
    ofs[tx] = c ? atomicAdd(&bktCursor[tx], c) : 0;   // bulk reservation
    cnt[tx] = 0;                                       // reuse as local cursor
    __syncthreads();
    for (int i = be + tx; i < ee; i += 256) {
        int d = dst[i];
        int b = d >> BKTSH;
        int l = atomicAdd(&cnt[b], 1);
        bin[ofs[b] + l] = ((d & 511) << 17) | src[i];  // src < 2^17
    }
}

// ---------------- binA_src: same, but payload = src&511 as u16 (degree count only) ------
__global__ __launch_bounds__(256) void binAs_kernel(
    const int* __restrict__ src,
    int* __restrict__ bktCursor, unsigned short* __restrict__ bin2, int E) {
    __shared__ int cnt[NBKT];
    __shared__ int ofs[NBKT];
    const int tx = threadIdx.x;
    const int be = blockIdx.x * CH;
    const int ee = min(be + CH, E);
    cnt[tx] = 0;
    __syncthreads();
    for (int i = be + tx; i < ee; i += 256)
        atomicAdd(&cnt[src[i] >> BKTSH], 1);
    __syncthreads();
    int c = cnt[tx];
    ofs[tx] = c ? atomicAdd(&bktCursor[tx], c) : 0;
    cnt[tx] = 0;
    __syncthreads();
    for (int i = be + tx; i < ee; i += 256) {
        int s = src[i];
        int b = s >> BKTSH;
        int l = atomicAdd(&cnt[b], 1);
        bin2[ofs[b] + l] = (unsigned short)(s & 511);
    }
}

// ---------------- passB_dst: per-bucket (512 nodes) LDS counting sort ----------------
__global__ __launch_bounds__(256) void passB_kernel(
    const int* __restrict__ bktBase, const int* __restrict__ bin,
    int* __restrict__ csr_src, int* __restrict__ row_ptr, float* __restrict__ rs_in, int N) {
    __shared__ int cnt[512];
    __shared__ int cur[512];
    __shared__ int part[256];
    const int b = blockIdx.x;
    const int base = bktBase[b], end = bktBase[b + 1];
    const int tx = threadIdx.x;
    cnt[tx] = 0; cnt[tx + 256] = 0;
    __syncthreads();
    for (int i = base + tx; i < end; i += 256)
        atomicAdd(&cnt[bin[i] >> 17], 1);
    __syncthreads();
    int a0 = cnt[2 * tx], a1 = cnt[2 * tx + 1];
    part[tx] = a0 + a1;
    __syncthreads();
    for (int off = 1; off < 256; off <<= 1) {
        int v = (tx >= off) ? part[tx - off] : 0;
        __syncthreads();
        part[tx] += v;
        __syncthreads();
    }
    int excl = part[tx] - (a0 + a1);
    cur[2 * tx] = excl;
    cur[2 * tx + 1] = excl + a0;
    int idx = (b << BKTSH) + 2 * tx;
    row_ptr[idx]     = base + excl;
    row_ptr[idx + 1] = base + excl + a0;
    if (idx < N)     rs_in[idx]     = rsqrtf((float)max(a0, 1));
    if (idx + 1 < N) rs_in[idx + 1] = rsqrtf((float)max(a1, 1));
    __syncthreads();
    for (int i = base + tx; i < end; i += 256) {
        int v = bin[i];
        int nl = v >> 17;
        int p = atomicAdd(&cur[nl], 1);
        csr_src[base + p] = v & 0x1FFFF;
    }
}

// ---------------- passB_src: per-bucket out-degree histogram -> rs_out ----------------
__global__ __launch_bounds__(256) void passBs_kernel(
    const int* __restrict__ bktBase2, const unsigned short* __restrict__ bin2,
    float* __restrict__ rs_out, int N) {
    __shared__ int cnt[512];
    const int b = blockIdx.x;
    const int base = bktBase2[b], end = bktBase2[b + 1];
    const int tx = threadIdx.x;
    cnt[tx] = 0; cnt[tx + 256] = 0;
    __syncthreads();
    for (int i = base + tx; i < end; i += 256)
        atomicAdd(&cnt[bin2[i]], 1);
    __syncthreads();
    int idx = (b << BKTSH) + tx;
    if (idx < N)       rs_out[idx]       = rsqrtf((float)max(cnt[tx], 1));
    if (idx + 256 < N) rs_out[idx + 256] = rsqrtf((float)max(cnt[tx + 256], 1));
}

// ---------------- GEMM1 (MFMA bf16): h1b = bf16((x*rs_out) @ W1)  [N,256]@[256,128] ------
__global__ __launch_bounds__(256) void gemm1_kernel(
    const float* __restrict__ x, const float* __restrict__ W1,
    const float* __restrict__ rs_out, unsigned short* __restrict__ h1b, int N) {
    __shared__ unsigned short Wl[32768];  // 64 KB

    const int tx = threadIdx.x;
#pragma unroll
    for (int e = 0; e < 32; ++e) {
        int base = (tx + 256 * e) * 4;
        float4 w = *(const float4*)&W1[base];
        int k = base >> 7;
        int c0 = base & 127;
        float wv[4] = {w.x, w.y, w.z, w.w};
#pragma unroll
        for (int q = 0; q < 4; ++q) {
            int col = c0 + q;
            int byte = col * 512 + k * 2;
            byte ^= (col & 7) << 4;
            Wl[byte >> 1] = f2bf(wv[q]);
        }
    }
    __syncthreads();

    const int wv_ = tx >> 6, lane = tx & 63;
    const int r0 = blockIdx.x * 64 + wv_ * 16;
    const int arow = r0 + (lane & 15);
    const int arow_c = min(arow, N - 1);
    const float rs = rs_out[arow_c];
    const long xbase = (long)arow_c * IN_F + (lane >> 4) * 8;

    bf16x8 a8[8];
#pragma unroll
    for (int ks = 0; ks < 8; ++ks) {
        float4 p0 = *(const float4*)&x[xbase + ks * 32];
        float4 p1 = *(const float4*)&x[xbase + ks * 32 + 4];
        bf16x8 a;
        a[0] = (short)f2bf(p0.x * rs); a[1] = (short)f2bf(p0.y * rs);
        a[2] = (short)f2bf(p0.z * rs); a[3] = (short)f2bf(p0.w * rs);
        a[4] = (short)f2bf(p1.x * rs); a[5] = (short)f2bf(p1.y * rs);
        a[6] = (short)f2bf(p1.z * rs); a[7] = (short)f2bf(p1.w * rs);
        a8[ks] = a;
    }

    f32x4 acc[8];
#pragma unroll
    for (int nf = 0; nf < 8; ++nf) acc[nf] = (f32x4){0.f, 0.f, 0.f, 0.f};

#pragma unroll
    for (int ks = 0; ks < 8; ++ks) {
#pragma unroll
        for (int nf = 0; nf < 8; ++nf) {
            int col = nf * 16 + (lane & 15);
            int kb  = ks * 32 + (lane >> 4) * 8;
            int byte = col * 512 + kb * 2;
            byte ^= (col & 7) << 4;
            bf16x8 b = *(const bf16x8*)((const char*)Wl + byte);
            acc[nf] = __builtin_amdgcn_mfma_f32_16x16x32_bf16(a8[ks], b, acc[nf], 0, 0, 0);
        }
    }

#pragma unroll
    for (int nf = 0; nf < 8; ++nf) {
#pragma unroll
        for (int j = 0; j < 4; ++j) {
            int row = r0 + (lane >> 4) * 4 + j;
            if (row < N)
                h1b[(long)row * HID + nf * 16 + (lane & 15)] = f2bf(acc[nf][j]);
        }
    }
}

// ---------------- agg1 (pull): agg[n] = sum h1b[src]  (bf16 gather, f32 accum) ----------
__global__ __launch_bounds__(256) void agg1_kernel(
    const int* __restrict__ row_ptr, const int* __restrict__ row_end,
    const int* __restrict__ csr_src, const unsigned* __restrict__ h1b2,  // [N][64] uint
    float* __restrict__ agg, int N) {
    int node = (blockIdx.x * 256 + threadIdx.x) >> 6;
    int lane = threadIdx.x & 63;
    if (node >= N) return;
    int e = row_ptr[node], end = row_end[node];
    float ax = 0.f, ay = 0.f;
    for (; e + 4 <= end; e += 4) {
        int s0 = csr_src[e], s1 = csr_src[e + 1], s2 = csr_src[e + 2], s3 = csr_src[e + 3];
        unsigned u0 = h1b2[(long)s0 * 64 + lane];
        unsigned u1 = h1b2[(long)s1 * 64 + lane];
        unsigned u2 = h1b2[(long)s2 * 64 + lane];
        unsigned u3 = h1b2[(long)s3 * 64 + lane];
        ax += __builtin_bit_cast(float, u0 << 16) + __builtin_bit_cast(float, u1 << 16)
            + __builtin_bit_cast(float, u2 << 16) + __builtin_bit_cast(float, u3 << 16);
        ay += __builtin_bit_cast(float, u0 & 0xffff0000u) + __builtin_bit_cast(float, u1 & 0xffff0000u)
            + __builtin_bit_cast(float, u2 & 0xffff0000u) + __builtin_bit_cast(float, u3 & 0xffff0000u);
    }
    for (; e < end; ++e) {
        unsigned u = h1b2[(long)csr_src[e] * 64 + lane];
        ax += __builtin_bit_cast(float, u << 16);
        ay += __builtin_bit_cast(float, u & 0xffff0000u);
    }
    float2 o; o.x = ax; o.y = ay;
    *(float2*)&agg[(long)node * HID + 2 * lane] = o;
}

// -------- GEMM2 (MFMA bf16): h2b = bf16((relu(agg*rs_in+b1)*rs_out) @ W2) [N,128]@[128,40]
__global__ __launch_bounds__(256) void gemm2_kernel(
    const float* __restrict__ agg1, const float* __restrict__ W2,
    const float* __restrict__ b1, const float* __restrict__ rs_in,
    const float* __restrict__ rs_out, unsigned short* __restrict__ h2b, int N) {
    __shared__ unsigned short Wl[48 * 128];  // 12 KB

    const int tx = threadIdx.x;
    for (int idx = tx; idx < 48 * 128; idx += 256) Wl[idx] = 0;
    __syncthreads();
    for (int idx = tx; idx < 128 * NCLS; idx += 256) {
        int k = idx / NCLS, c = idx - k * NCLS;
        int byte = c * 256 + k * 2;
        byte ^= (c & 7) << 4;
        Wl[byte >> 1] = f2bf(W2[idx]);
    }
    __syncthreads();

    const int wv_ = tx >> 6, lane = tx & 63;
    const int r0 = blockIdx.x * 64 + wv_ * 16;
    const int arow = r0 + (lane & 15);
    const int arow_c = min(arow, N - 1);
    const float ri = rs_in[arow_c];
    const float ro = rs_out[arow_c];
    const int k0 = (lane >> 4) * 8;
    const long abase = (long)arow_c * HID + k0;

    bf16x8 a8[4];
#pragma unroll
    for (int ks = 0; ks < 4; ++ks) {
        float4 p0 = *(const float4*)&agg1[abase + ks * 32];
        float4 p1 = *(const float4*)&agg1[abase + ks * 32 + 4];
        float4 c0 = *(const float4*)&b1[k0 + ks * 32];
        float4 c1 = *(const float4*)&b1[k0 + ks * 32 + 4];
        bf16x8 a;
        a[0] = (short)f2bf(fmaxf(fmaf(p0.x, ri, c0.x), 0.f) * ro);
        a[1] = (short)f2bf(fmaxf(fmaf(p0.y, ri, c0.y), 0.f) * ro);
        a[2] = (short)f2bf(fmaxf(fmaf(p0.z, ri, c0.z), 0.f) * ro);
        a[3] = (short)f2bf(fmaxf(fmaf(p0.w, ri, c0.w), 0.f) * ro);
        a[4] = (short)f2bf(fmaxf(fmaf(p1.x, ri, c1.x), 0.f) * ro);
        a[5] = (short)f2bf(fmaxf(fmaf(p1.y, ri, c1.y), 0.f) * ro);
        a[6] = (short)f2bf(fmaxf(fmaf(p1.z, ri, c1.z), 0.f) * ro);
        a[7] = (short)f2bf(fmaxf(fmaf(p1.w, ri, c1.w), 0.f) * ro);
        a8[ks] = a;
    }

    f32x4 acc[3];
#pragma unroll
    for (int nf = 0; nf < 3; ++nf) acc[nf] = (f32x4){0.f, 0.f, 0.f, 0.f};

#pragma unroll
    for (int ks = 0; ks < 4; ++ks) {
#pragma unroll
        for (int nf = 0; nf < 3; ++nf) {
            int col = nf * 16 + (lane & 15);
            int kb  = ks * 32 + k0;
            int byte = col * 256 + kb * 2;
            byte ^= (col & 7) << 4;
            bf16x8 b = *(const bf16x8*)((const char*)Wl + byte);
            acc[nf] = __builtin_amdgcn_mfma_f32_16x16x32_bf16(a8[ks], b, acc[nf], 0, 0, 0);
        }
    }

#pragma unroll
    for (int nf = 0; nf < 3; ++nf) {
        int col = nf * 16 + (lane & 15);
        if (col < NCLS) {
#pragma unroll
            for (int j = 0; j < 4; ++j) {
                int row = r0 + (lane >> 4) * 4 + j;
                if (row < N)
                    h2b[(long)row * NCLS + col] = f2bf(acc[nf][j]);
            }
        }
    }
}

// ---------------- agg2 (pull) + epilogue: thread per (node, col-pair) -------------------
__global__ __launch_bounds__(256) void agg2_kernel(
    const int* __restrict__ row_ptr, const int* __restrict__ row_end,
    const int* __restrict__ csr_src, const unsigned* __restrict__ h2b2,  // [N][20] uint
    const float* __restrict__ rs_in, const float* __restrict__ b2,
    float* __restrict__ out, int N) {
    int i = blockIdx.x * 256 + threadIdx.x;
    if (i >= N * 20) return;
    int node = i / 20;
    int cp   = i - node * 20;
    int e = row_ptr[node], end = row_end[node];
    float ax = 0.f, ay = 0.f;
    for (; e + 4 <= end; e += 4) {
        int s0 = csr_src[e], s1 = csr_src[e + 1], s2 = csr_src[e + 2], s3 = csr_src[e + 3];
        unsigned u0 = h2b2[(long)s0 * 20 + cp];
        unsigned u1 = h2b2[(long)s1 * 20 + cp];
        unsigned u2 = h2b2[(long)s2 * 20 + cp];
        unsigned u3 = h2b2[(long)s3 * 20 + cp];
        ax += __builtin_bit_cast(float, u0 << 16) + __builtin_bit_cast(float, u1 << 16)
            + __builtin_bit_cast(float, u2 << 16) + __builtin_bit_cast(float, u3 << 16);
        ay += __builtin_bit_cast(float, u0 & 0xffff0000u) + __builtin_bit_cast(float, u1 & 0xffff0000u)
            + __builtin_bit_cast(float, u2 & 0xffff0000u) + __builtin_bit_cast(float, u3 & 0xffff0000u);
    }
    for (; e < end; ++e) {
        unsigned u = h2b2[(long)csr_src[e] * 20 + cp];
        ax += __builtin_bit_cast(float, u << 16);
        ay += __builtin_bit_cast(float, u & 0xffff0000u);
    }
    float r = rs_in[node];
    float2 o;
    o.x = fmaf(ax, r, b2[2 * cp]);
    o.y = fmaf(ay, r, b2[2 * cp + 1]);
    *(float2*)&out[(long)node * NCLS + 2 * cp] = o;
}

extern "C" void kernel_launch(void* const* d_in, const int* in_sizes, int n_in,
                              void* d_out, int out_size, void* d_ws, size_t ws_size,
                              hipStream_t stream) {
    const float* x  = (const float*)d_in[0];
    const float* W1 = (const float*)d_in[1];
    const float* b1 = (const float*)d_in[2];
    const float* W2 = (const float*)d_in[3];
    const float* b2 = (const float*)d_in[4];
    const int*  src = (const int*)d_in[5];
    const int*  dst = (const int*)d_in[6];
    const int N = in_sizes[0] / IN_F;
    const int E = in_sizes[5];
    const int NBLK = (N + 511) >> BKTSH;   // node buckets in use

    float* wsf       = (float*)d_ws;
    float* rs_out    = wsf;                          // N f
    float* rs_in     = wsf + N;                      // N f
    int*   bktCntD   = (int*)(wsf + 2 * (long)N);    // NBKT (zeroed)
    int*   bktCntS   = bktCntD + NBKT;               // NBKT (zeroed)
    int*   bktBaseD  = bktCntS + NBKT;               // NBKT+1
    int*   bktCursorD= bktBaseD + NBKT + 1;          // NBKT
    int*   bktBaseS  = bktCursorD + NBKT;            // NBKT+1
    int*   bktCursorS= bktBaseS + NBKT + 1;          // NBKT
    int*   row_ptr   = bktCursorS + NBKT;            // N+1024
    int*   bin       = row_ptr + N + 1024;           // E i
    int*   csr_src   = bin + E;                      // E i
    unsigned short* bin2 = (unsigned short*)(csr_src + E);         // E u16
    unsigned short* h1b  = bin2 + E;                               // N*128 bf16
    float* agg1      = (float*)(h1b + (long)N * HID);              // N*128 f
    unsigned short* h2b  = (unsigned short*)(agg1 + (long)N * HID);// N*40 bf16

    zero_kernel<<<2, 256, 0, stream>>>(bktCntD, 2 * NBKT);

    count_kernel<<<256, 256, 0, stream>>>(src, dst, bktCntD, bktCntS, E);
    bscan_kernel<<<1, 256, 0, stream>>>(bktCntD, bktBaseD, bktCursorD);
    bscan_kernel<<<1, 256, 0, stream>>>(bktCntS, bktBaseS, bktCursorS);
    binA_kernel<<<(E + CH - 1) / CH, 256, 0, stream>>>(src, dst, bktCursorD, bin, E);
    binAs_kernel<<<(E + CH - 1) / CH, 256, 0, stream>>>(src, bktCursorS, bin2, E);
    passB_kernel<<<NBLK, 256, 0, stream>>>(bktBaseD, bin, csr_src, row_ptr, rs_in, N);
    passBs_kernel<<<NBLK, 256, 0, stream>>>(bktBaseS, bin2, rs_out, N);

    gemm1_kernel<<<(N + 63) / 64, 256, 0, stream>>>(x, W1, rs_out, h1b, N);
    agg1_kernel<<<(N * 64 + 255) / 256, 256, 0, stream>>>(row_ptr, row_ptr + 1, csr_src,
                                                          (const unsigned*)h1b, agg1, N);
    gemm2_kernel<<<(N + 63) / 64, 256, 0, stream>>>(agg1, W2, b1, rs_in, rs_out, h2b, N);
    agg2_kernel<<<(N * 20 + 255) / 256, 256, 0, stream>>>(row_ptr, row_ptr + 1, csr_src,
                                                          (const unsigned*)h2b, rs_in, b2,
                                                          (float*)d_out, N);
}

// Round 11
// 458.715 us; speedup vs baseline: 1.4485x; 1.0767x over previous
//
#include <hip/hip_runtime.h>

#define IN_F 256
#define HID  128
#define NCLS 40
#define NBKT 256        // coarse buckets of 512 nodes: supports N <= 131072
#define BKTSH 9         // 512 nodes per bucket
#define CH 16384        // edges per binning chunk

typedef __attribute__((ext_vector_type(8))) short bf16x8;
typedef __attribute__((ext_vector_type(4))) float f32x4;

static __device__ __forceinline__ unsigned short f2bf(float f) {
    unsigned u = __builtin_bit_cast(unsigned, f);
    u += 0x7fffu + ((u >> 16) & 1u);   // round-to-nearest-even
    return (unsigned short)(u >> 16);
}
static __device__ __forceinline__ float bf2f(unsigned short b) {
    return __builtin_bit_cast(float, ((unsigned)b) << 16);
}

// ---------------- zero (tiny: bucket counters only) ----------------
__global__ void zero_kernel(int* __restrict__ p, int n) {
    int i = blockIdx.x * blockDim.x + threadIdx.x;
    if (i < n) p[i] = 0;
}

// ---------------- count: LDS bucket histograms for BOTH src and dst ----------------
__global__ __launch_bounds__(256) void count_kernel(
    const int* __restrict__ src, const int* __restrict__ dst,
    int* __restrict__ bktCntD, int* __restrict__ bktCntS, int E) {
    __shared__ int histD[NBKT];
    __shared__ int histS[NBKT];
    histD[threadIdx.x] = 0;
    histS[threadIdx.x] = 0;
    __syncthreads();
    int stride = gridDim.x * 256;
    for (int i = blockIdx.x * 256 + threadIdx.x; i < E; i += stride) {
        atomicAdd(&histD[dst[i] >> BKTSH], 1);
        atomicAdd(&histS[src[i] >> BKTSH], 1);
    }
    __syncthreads();
    int c = histD[threadIdx.x];
    if (c) atomicAdd(&bktCntD[threadIdx.x], c);
    c = histS[threadIdx.x];
    if (c) atomicAdd(&bktCntS[threadIdx.x], c);
}

// ---------------- bucket exclusive scan (one block, 256 entries) ----------------
__global__ __launch_bounds__(256) void bscan_kernel(const int* __restrict__ bktCnt,
                                                    int* __restrict__ bktBase,
                                                    int* __restrict__ bktCursor) {
    __shared__ int s[256];
    int t = threadIdx.x;
    int v = bktCnt[t];
    s[t] = v;
    __syncthreads();
    for (int off = 1; off < 256; off <<= 1) {
        int u = (t >= off) ? s[t - off] : 0;
        __syncthreads();
        s[t] += u;
        __syncthreads();
    }
    int excl = s[t] - v;
    bktBase[t] = excl;
    bktCursor[t] = excl;
    if (t == 255) bktBase[256] = s[t];   // total = E
}

// ---------------- binBoth: one chunked pass produces dst-bin AND src-bin ----------------
__global__ __launch_bounds__(256) void binBoth_kernel(
    const int* __restrict__ src, const int* __restrict__ dst,
    int* __restrict__ curD, int* __restrict__ curS,
    int* __restrict__ bin, unsigned short* __restrict__ bin2, int E) {
    __shared__ int cntD[NBKT], ofsD[NBKT];
    __shared__ int cntS[NBKT], ofsS[NBKT];
    const int tx = threadIdx.x;
    const int be = blockIdx.x * CH;
    const int ee = min(be + CH, E);
    cntD[tx] = 0; cntS[tx] = 0;
    __syncthreads();
    for (int i = be + tx; i < ee; i += 256) {
        atomicAdd(&cntD[dst[i] >> BKTSH], 1);
        atomicAdd(&cntS[src[i] >> BKTSH], 1);
    }
    __syncthreads();
    int c = cntD[tx];
    ofsD[tx] = c ? atomicAdd(&curD[tx], c) : 0;
    cntD[tx] = 0;
    c = cntS[tx];
    ofsS[tx] = c ? atomicAdd(&curS[tx], c) : 0;
    cntS[tx] = 0;
    __syncthreads();
    for (int i = be + tx; i < ee; i += 256) {
        int d = dst[i], s = src[i];
        int b = d >> BKTSH;
        int l = atomicAdd(&cntD[b], 1);
        bin[ofsD[b] + l] = ((d & 511) << 17) | s;      // src < 2^17
        int b2 = s >> BKTSH;
        int l2 = atomicAdd(&cntS[b2], 1);
        bin2[ofsS[b2] + l2] = (unsigned short)(s & 511);
    }
}

// ---------------- passB_dst: per-bucket (512 nodes) LDS counting sort ----------------
__global__ __launch_bounds__(256) void passB_kernel(
    const int* __restrict__ bktBase, const int* __restrict__ bin,
    int* __restrict__ csr_src, int* __restrict__ row_ptr, float* __restrict__ rs_in, int N) {
    __shared__ int cnt[512];
    __shared__ int cur[512];
    __shared__ int part[256];
    const int b = blockIdx.x;
    const int base = bktBase[b], end = bktBase[b + 1];
    const int tx = threadIdx.x;
    cnt[tx] = 0; cnt[tx + 256] = 0;
    __syncthreads();
    for (int i = base + tx; i < end; i += 256)
        atomicAdd(&cnt[bin[i] >> 17], 1);
    __syncthreads();
    int a0 = cnt[2 * tx], a1 = cnt[2 * tx + 1];
    part[tx] = a0 + a1;
    __syncthreads();
    for (int off = 1; off < 256; off <<= 1) {
        int v = (tx >= off) ? part[tx - off] : 0;
        __syncthreads();
        part[tx] += v;
        __syncthreads();
    }
    int excl = part[tx] - (a0 + a1);
    cur[2 * tx] = excl;
    cur[2 * tx + 1] = excl + a0;
    int idx = (b << BKTSH) + 2 * tx;
    row_ptr[idx]     = base + excl;
    row_ptr[idx + 1] = base + excl + a0;
    if (idx < N)     rs_in[idx]     = rsqrtf((float)max(a0, 1));
    if (idx + 1 < N) rs_in[idx + 1] = rsqrtf((float)max(a1, 1));
    __syncthreads();
    for (int i = base + tx; i < end; i += 256) {
        int v = bin[i];
        int nl = v >> 17;
        int p = atomicAdd(&cur[nl], 1);
        csr_src[base + p] = v & 0x1FFFF;
    }
}

// ---------------- passB_src: per-bucket out-degree histogram -> rs_out ----------------
__global__ __launch_bounds__(256) void passBs_kernel(
    const int* __restrict__ bktBase2, const unsigned short* __restrict__ bin2,
    float* __restrict__ rs_out, int N) {
    __shared__ int cnt[512];
    const int b = blockIdx.x;
    const int base = bktBase2[b], end = bktBase2[b + 1];
    const int tx = threadIdx.x;
    cnt[tx] = 0; cnt[tx + 256] = 0;
    __syncthreads();
    for (int i = base + tx; i < end; i += 256)
        atomicAdd(&cnt[bin2[i]], 1);
    __syncthreads();
    int idx = (b << BKTSH) + tx;
    if (idx < N)       rs_out[idx]       = rsqrtf((float)max(cnt[tx], 1));
    if (idx + 256 < N) rs_out[idx + 256] = rsqrtf((float)max(cnt[tx + 256], 1));
}

// ---------------- GEMM1 (MFMA bf16): h1b = bf16((x*rs_out) @ W1)  [N,256]@[256,128] ------
__global__ __launch_bounds__(256) void gemm1_kernel(
    const float* __restrict__ x, const float* __restrict__ W1,
    const float* __restrict__ rs_out, unsigned short* __restrict__ h1b, int N) {
    __shared__ unsigned short Wl[32768];  // 64 KB

    const int tx = threadIdx.x;
#pragma unroll
    for (int e = 0; e < 32; ++e) {
        int base = (tx + 256 * e) * 4;
        float4 w = *(const float4*)&W1[base];
        int k = base >> 7;
        int c0 = base & 127;
        float wv[4] = {w.x, w.y, w.z, w.w};
#pragma unroll
        for (int q = 0; q < 4; ++q) {
            int col = c0 + q;
            int byte = col * 512 + k * 2;
            byte ^= (col & 7) << 4;
            Wl[byte >> 1] = f2bf(wv[q]);
        }
    }
    __syncthreads();

    const int wv_ = tx >> 6, lane = tx & 63;
    const int r0 = blockIdx.x * 64 + wv_ * 16;
    const int arow = r0 + (lane & 15);
    const int arow_c = min(arow, N - 1);
    const float rs = rs_out[arow_c];
    const long xbase = (long)arow_c * IN_F + (lane >> 4) * 8;

    bf16x8 a8[8];
#pragma unroll
    for (int ks = 0; ks < 8; ++ks) {
        float4 p0 = *(const float4*)&x[xbase + ks * 32];
        float4 p1 = *(const float4*)&x[xbase + ks * 32 + 4];
        bf16x8 a;
        a[0] = (short)f2bf(p0.x * rs); a[1] = (short)f2bf(p0.y * rs);
        a[2] = (short)f2bf(p0.z * rs); a[3] = (short)f2bf(p0.w * rs);
        a[4] = (short)f2bf(p1.x * rs); a[5] = (short)f2bf(p1.y * rs);
        a[6] = (short)f2bf(p1.z * rs); a[7] = (short)f2bf(p1.w * rs);
        a8[ks] = a;
    }

    f32x4 acc[8];
#pragma unroll
    for (int nf = 0; nf < 8; ++nf) acc[nf] = (f32x4){0.f, 0.f, 0.f, 0.f};

#pragma unroll
    for (int ks = 0; ks < 8; ++ks) {
#pragma unroll
        for (int nf = 0; nf < 8; ++nf) {
            int col = nf * 16 + (lane & 15);
            int kb  = ks * 32 + (lane >> 4) * 8;
            int byte = col * 512 + kb * 2;
            byte ^= (col & 7) << 4;
            bf16x8 b = *(const bf16x8*)((const char*)Wl + byte);
            acc[nf] = __builtin_amdgcn_mfma_f32_16x16x32_bf16(a8[ks], b, acc[nf], 0, 0, 0);
        }
    }

#pragma unroll
    for (int nf = 0; nf < 8; ++nf) {
#pragma unroll
        for (int j = 0; j < 4; ++j) {
            int row = r0 + (lane >> 4) * 4 + j;
            if (row < N)
                h1b[(long)row * HID + nf * 16 + (lane & 15)] = f2bf(acc[nf][j]);
        }
    }
}

// ---------------- agg1 (pull): aggb[n] = bf16(sum h1b[src])  (unroll 8) -----------------
__global__ __launch_bounds__(256) void agg1_kernel(
    const int* __restrict__ row_ptr, const int* __restrict__ row_end,
    const int* __restrict__ csr_src, const unsigned* __restrict__ h1b2,  // [N][64] uint
    unsigned* __restrict__ aggb, int N) {                                // [N][64] uint (bf16x2)
    int node = (blockIdx.x * 256 + threadIdx.x) >> 6;
    int lane = threadIdx.x & 63;
    if (node >= N) return;
    int e = row_ptr[node], end = row_end[node];
    float ax = 0.f, ay = 0.f;
    for (; e + 8 <= end; e += 8) {
        int s0 = csr_src[e],     s1 = csr_src[e + 1], s2 = csr_src[e + 2], s3 = csr_src[e + 3];
        int s4 = csr_src[e + 4], s5 = csr_src[e + 5], s6 = csr_src[e + 6], s7 = csr_src[e + 7];
        unsigned u0 = h1b2[(long)s0 * 64 + lane];
        unsigned u1 = h1b2[(long)s1 * 64 + lane];
        unsigned u2 = h1b2[(long)s2 * 64 + lane];
        unsigned u3 = h1b2[(long)s3 * 64 + lane];
        unsigned u4 = h1b2[(long)s4 * 64 + lane];
        unsigned u5 = h1b2[(long)s5 * 64 + lane];
        unsigned u6 = h1b2[(long)s6 * 64 + lane];
        unsigned u7 = h1b2[(long)s7 * 64 + lane];
        ax += (__builtin_bit_cast(float, u0 << 16) + __builtin_bit_cast(float, u1 << 16))
            + (__builtin_bit_cast(float, u2 << 16) + __builtin_bit_cast(float, u3 << 16))
            + (__builtin_bit_cast(float, u4 << 16) + __builtin_bit_cast(float, u5 << 16))
            + (__builtin_bit_cast(float, u6 << 16) + __builtin_bit_cast(float, u7 << 16));
        ay += (__builtin_bit_cast(float, u0 & 0xffff0000u) + __builtin_bit_cast(float, u1 & 0xffff0000u))
            + (__builtin_bit_cast(float, u2 & 0xffff0000u) + __builtin_bit_cast(float, u3 & 0xffff0000u))
            + (__builtin_bit_cast(float, u4 & 0xffff0000u) + __builtin_bit_cast(float, u5 & 0xffff0000u))
            + (__builtin_bit_cast(float, u6 & 0xffff0000u) + __builtin_bit_cast(float, u7 & 0xffff0000u));
    }
    for (; e < end; ++e) {
        unsigned u = h1b2[(long)csr_src[e] * 64 + lane];
        ax += __builtin_bit_cast(float, u << 16);
        ay += __builtin_bit_cast(float, u & 0xffff0000u);
    }
    aggb[(long)node * 64 + lane] = ((unsigned)f2bf(ay) << 16) | (unsigned)f2bf(ax);
}

// -------- GEMM2 (MFMA bf16): h2p = bf16((relu(aggb*rs_in+b1)*rs_out) @ W2), rows padded 64
__global__ __launch_bounds__(256) void gemm2_kernel(
    const unsigned short* __restrict__ aggb, const float* __restrict__ W2,
    const float* __restrict__ b1, const float* __restrict__ rs_in,
    const float* __restrict__ rs_out, unsigned short* __restrict__ h2p, int N) {
    __shared__ unsigned short Wl[48 * 128];  // 12 KB

    const int tx = threadIdx.x;
    for (int idx = tx; idx < 48 * 128; idx += 256) Wl[idx] = 0;
    __syncthreads();
    for (int idx = tx; idx < 128 * NCLS; idx += 256) {
        int k = idx / NCLS, c = idx - k * NCLS;
        int byte = c * 256 + k * 2;
        byte ^= (c & 7) << 4;
        Wl[byte >> 1] = f2bf(W2[idx]);
    }
    __syncthreads();

    const int wv_ = tx >> 6, lane = tx & 63;
    const int r0 = blockIdx.x * 64 + wv_ * 16;
    const int arow = r0 + (lane & 15);
    const int arow_c = min(arow, N - 1);
    const float ri = rs_in[arow_c];
    const float ro = rs_out[arow_c];
    const int k0 = (lane >> 4) * 8;
    const long abase = (long)arow_c * HID + k0;

    bf16x8 a8[4];
#pragma unroll
    for (int ks = 0; ks < 4; ++ks) {
        bf16x8 ar = *(const bf16x8*)&aggb[abase + ks * 32];
        float4 c0 = *(const float4*)&b1[k0 + ks * 32];
        float4 c1 = *(const float4*)&b1[k0 + ks * 32 + 4];
        float bv[8] = {c0.x, c0.y, c0.z, c0.w, c1.x, c1.y, c1.z, c1.w};
        bf16x8 a;
#pragma unroll
        for (int j = 0; j < 8; ++j)
            a[j] = (short)f2bf(fmaxf(fmaf(bf2f((unsigned short)ar[j]), ri, bv[j]), 0.f) * ro);
        a8[ks] = a;
    }

    f32x4 acc[3];
#pragma unroll
    for (int nf = 0; nf < 3; ++nf) acc[nf] = (f32x4){0.f, 0.f, 0.f, 0.f};

#pragma unroll
    for (int ks = 0; ks < 4; ++ks) {
#pragma unroll
        for (int nf = 0; nf < 3; ++nf) {
            int col = nf * 16 + (lane & 15);
            int kb  = ks * 32 + k0;
            int byte = col * 256 + kb * 2;
            byte ^= (col & 7) << 4;
            bf16x8 b = *(const bf16x8*)((const char*)Wl + byte);
            acc[nf] = __builtin_amdgcn_mfma_f32_16x16x32_bf16(a8[ks], b, acc[nf], 0, 0, 0);
        }
    }

#pragma unroll
    for (int nf = 0; nf < 3; ++nf) {
        int col = nf * 16 + (lane & 15);
        if (col < NCLS) {
#pragma unroll
            for (int j = 0; j < 4; ++j) {
                int row = r0 + (lane >> 4) * 4 + j;
                if (row < N)
                    h2p[(long)row * 64 + col] = f2bf(acc[nf][j]);
            }
        }
    }
}

// ---------------- agg2 (pull) + epilogue: thread per (node, col-pair), 128B rows --------
__global__ __launch_bounds__(256) void agg2_kernel(
    const int* __restrict__ row_ptr, const int* __restrict__ row_end,
    const int* __restrict__ csr_src, const unsigned* __restrict__ h2p2,  // [N][32] uint
    const float* __restrict__ rs_in, const float* __restrict__ b2,
    float* __restrict__ out, int N) {
    int i = blockIdx.x * 256 + threadIdx.x;
    if (i >= N * 20) return;
    int node = i / 20;
    int cp   = i - node * 20;
    int e = row_ptr[node], end = row_end[node];
    float ax = 0.f, ay = 0.f;
    for (; e + 4 <= end; e += 4) {
        int s0 = csr_src[e], s1 = csr_src[e + 1], s2 = csr_src[e + 2], s3 = csr_src[e + 3];
        unsigned u0 = h2p2[(long)s0 * 32 + cp];
        unsigned u1 = h2p2[(long)s1 * 32 + cp];
        unsigned u2 = h2p2[(long)s2 * 32 + cp];
        unsigned u3 = h2p2[(long)s3 * 32 + cp];
        ax += __builtin_bit_cast(float, u0 << 16) + __builtin_bit_cast(float, u1 << 16)
            + __builtin_bit_cast(float, u2 << 16) + __builtin_bit_cast(float, u3 << 16);
        ay += __builtin_bit_cast(float, u0 & 0xffff0000u) + __builtin_bit_cast(float, u1 & 0xffff0000u)
            + __builtin_bit_cast(float, u2 & 0xffff0000u) + __builtin_bit_cast(float, u3 & 0xffff0000u);
    }
    for (; e < end; ++e) {
        unsigned u = h2p2[(long)csr_src[e] * 32 + cp];
        ax += __builtin_bit_cast(float, u << 16);
        ay += __builtin_bit_cast(float, u & 0xffff0000u);
    }
    float r = rs_in[node];
    float2 o;
    o.x = fmaf(ax, r, b2[2 * cp]);
    o.y = fmaf(ay, r, b2[2 * cp + 1]);
    *(float2*)&out[(long)node * NCLS + 2 * cp] = o;
}

extern "C" void kernel_launch(void* const* d_in, const int* in_sizes, int n_in,
                              void* d_out, int out_size, void* d_ws, size_t ws_size,
                              hipStream_t stream) {
    const float* x  = (const float*)d_in[0];
    const float* W1 = (const float*)d_in[1];
    const float* b1 = (const float*)d_in[2];
    const float* W2 = (const float*)d_in[3];
    const float* b2 = (const float*)d_in[4];
    const int*  src = (const int*)d_in[5];
    const int*  dst = (const int*)d_in[6];
    const int N = in_sizes[0] / IN_F;
    const int E = in_sizes[5];
    const int NBLK = (N + 511) >> BKTSH;   // node buckets in use

    float* wsf       = (float*)d_ws;
    float* rs_out    = wsf;                          // N f
    float* rs_in     = wsf + N;                      // N f
    int*   bktCntD   = (int*)(wsf + 2 * (long)N);    // NBKT (zeroed)
    int*   bktCntS   = bktCntD + NBKT;               // NBKT (zeroed)
    int*   bktBaseD  = bktCntS + NBKT;               // NBKT+1
    int*   bktCursorD= bktBaseD + NBKT + 1;          // NBKT
    int*   bktBaseS  = bktCursorD + NBKT;            // NBKT+1
    int*   bktCursorS= bktBaseS + NBKT + 1;          // NBKT
    int*   row_ptr   = bktCursorS + NBKT;            // N+1024
    int*   bin       = row_ptr + N + 1024;           // E i
    int*   csr_src   = bin + E;                      // E i
    unsigned short* bin2 = (unsigned short*)(csr_src + E);         // E u16
    unsigned short* h1b  = bin2 + E;                               // N*128 bf16
    unsigned short* aggb = h1b + (long)N * HID;                    // N*128 bf16
    unsigned short* h2p  = aggb + (long)N * HID;                   // N*64 bf16 (padded rows)

    zero_kernel<<<2, 256, 0, stream>>>(bktCntD, 2 * NBKT);

    count_kernel<<<256, 256, 0, stream>>>(src, dst, bktCntD, bktCntS, E);
    bscan_kernel<<<1, 256, 0, stream>>>(bktCntD, bktBaseD, bktCursorD);
    bscan_kernel<<<1, 256, 0, stream>>>(bktCntS, bktBaseS, bktCursorS);
    binBoth_kernel<<<(E + CH - 1) / CH, 256, 0, stream>>>(src, dst, bktCursorD, bktCursorS,
                                                          bin, bin2, E);
    passB_kernel<<<NBLK, 256, 0, stream>>>(bktBaseD, bin, csr_src, row_ptr, rs_in, N);
    passBs_kernel<<<NBLK, 256, 0, stream>>>(bktBaseS, bin2, rs_out, N);

    gemm1_kernel<<<(N + 63) / 64, 256, 0, stream>>>(x, W1, rs_out, h1b, N);
    agg1_kernel<<<(N * 64 + 255) / 256, 256, 0, stream>>>(row_ptr, row_ptr + 1, csr_src,
                                                          (const unsigned*)h1b,
                                                          (unsigned*)aggb, N);
    gemm2_kernel<<<(N + 63) / 64, 256, 0, stream>>>(aggb, W2, b1, rs_in, rs_out, h2p, N);
    agg2_kernel<<<(N * 20 + 255) / 256, 256, 0, stream>>>(row_ptr, row_ptr + 1, csr_src,
                                                          (const unsigned*)h2p, rs_in, b2,
                                                          (float*)d_out, N);
}